// Round 12
// baseline (270.826 us; speedup 1.0000x reference)
//
#include <hip/hip_runtime.h>
#include <hip/hip_fp16.h>

#define BATCH 16
#define NROW 1024
#define MCOL 1024
#define DFEAT 128

// DP blocking: one wave per batch, 16 rows/thread, 8 cols/phase
#define R_DP 16
#define C_DP 8
#define NCH (MCOL / C_DP)   // 128 chunks along j
#define NPH (NCH + 63)      // 191 real phases (192 executed)
#define PSTRIDE 194         // phase slots per batch (depth-2 prefetch horizon)

#define L2E 1.4426950408889634f
#define LN2 0.6931471805599453f

typedef __attribute__((ext_vector_type(8))) short short8;
typedef __attribute__((ext_vector_type(4))) float f32x4;

__device__ inline unsigned short f2bf(float f) {  // RNE f32 -> bf16 bits
  unsigned u = __float_as_uint(f);
  return (unsigned short)((u + 0x7fff + ((u >> 16) & 1)) >> 16);
}

// ---------------------------------------------------------------------------
// Kernel 1: normalize rows and emit bf16 copies. One wave per row.
// ---------------------------------------------------------------------------
__global__ __launch_bounds__(256) void norm_kernel(
    const float* __restrict__ x, const float* __restrict__ y,
    unsigned short* __restrict__ xnb, unsigned short* __restrict__ ynb) {
  int row = blockIdx.x * 4 + (threadIdx.x >> 6);
  int lane = threadIdx.x & 63;
  const float* src;
  unsigned short* dst;
  if (row < BATCH * NROW) {
    src = x + (size_t)row * DFEAT;
    dst = xnb + (size_t)row * DFEAT;
  } else {
    int r2 = row - BATCH * NROW;
    src = y + (size_t)r2 * DFEAT;
    dst = ynb + (size_t)r2 * DFEAT;
  }
  float2 v = *(const float2*)(src + lane * 2);
  float s = v.x * v.x + v.y * v.y;
  #pragma unroll
  for (int o = 32; o > 0; o >>= 1) s += __shfl_xor(s, o, 64);
  float inv = 1.0f / (sqrtf(s) + 1e-8f);
  unsigned short b0 = f2bf(v.x * inv), b1 = f2bf(v.y * inv);
  *(unsigned*)(dst + lane * 2) = (unsigned)b0 | ((unsigned)b1 << 16);
}

// ---------------------------------------------------------------------------
// Kernel 2: MFMA distance GEMM, 128x128 tile/block, 4 waves (2x2 of 64x64),
// bf16 16x16x32 MFMA. Epilogue stores exp(-(1-dot)) as fp16 in PHASE-MAJOR
// layout: Dphase[b][p][r][lane][k], p = (j>>3) + (i>>4), r = i&15, k = j&7 —
// the 16 KB a DP wave consumes at phase p is contiguous, and lane l's slot
// sits at lane-offset l (so a coalesced dwordx4 read IS the distribution).
// ---------------------------------------------------------------------------
__global__ __launch_bounds__(256) void dist_kernel(
    const unsigned short* __restrict__ xnb, const unsigned short* __restrict__ ynb,
    __half* __restrict__ Dphase) {
  __shared__ __align__(16) unsigned char xsb[128 * 256];
  __shared__ __align__(16) unsigned char ysb[128 * 256];

  int b = blockIdx.z, ti0 = blockIdx.y, tj0 = blockIdx.x;
  int I0 = ti0 * 128, J0 = tj0 * 128;
  int tid = threadIdx.x;

  const uint4* xsrc = (const uint4*)(xnb + (size_t)(b * NROW + I0) * DFEAT);
  const uint4* ysrc = (const uint4*)(ynb + (size_t)(b * MCOL + J0) * DFEAT);
  #pragma unroll
  for (int it = 0; it < 8; ++it) {
    int idx = tid + it * 256;           // 0..2047: row = idx>>4, 16B col = idx&15
    int row = idx >> 4, cb = (idx & 15) * 16;
    int swz = row * 256 + (cb ^ ((row & 7) << 4));
    *(uint4*)&xsb[swz] = xsrc[idx];
    *(uint4*)&ysb[swz] = ysrc[idx];
  }
  __syncthreads();

  int wid = tid >> 6, lane = tid & 63;
  int wi = wid >> 1, wj = wid & 1;      // 64x64 quadrant
  int lr = lane & 15, lk = lane >> 4;   // frag row = lr, k-group = lk

  f32x4 acc[4][4] = {};
  #pragma unroll
  for (int ks = 0; ks < 4; ++ks) {
    int cb = ks * 64 + lk * 16;
    short8 af[4], bf[4];
    #pragma unroll
    for (int ti = 0; ti < 4; ++ti) {
      int row = wi * 64 + ti * 16 + lr;
      af[ti] = *(short8*)&xsb[row * 256 + (cb ^ ((row & 7) << 4))];
    }
    #pragma unroll
    for (int tj = 0; tj < 4; ++tj) {
      int row = wj * 64 + tj * 16 + lr;
      bf[tj] = *(short8*)&ysb[row * 256 + (cb ^ ((row & 7) << 4))];
    }
    #pragma unroll
    for (int ti = 0; ti < 4; ++ti)
      #pragma unroll
      for (int tj = 0; tj < 4; ++tj)
        acc[ti][tj] = __builtin_amdgcn_mfma_f32_16x16x32_bf16(
            af[ti], bf[tj], acc[ti][tj], 0, 0, 0);
  }

  // epilogue: C/D layout col=lane&15, row=(lane>>4)*4+v; phase-major store
  #pragma unroll
  for (int ti = 0; ti < 4; ++ti) {
    int gi0 = I0 + wi * 64 + ti * 16;   // 16-aligned
    int l = gi0 >> 4;                   // DP lane owning these rows
    #pragma unroll
    for (int tj = 0; tj < 4; ++tj) {
      int gj = J0 + wj * 64 + tj * 16 + lr;
      int c = gj >> 3, k = gj & 7;
      int p = c + l;
      #pragma unroll
      for (int v = 0; v < 4; ++v) {
        int r = lk * 4 + v;
        float d = 1.0f - acc[ti][tj][v];
        size_t off = ((((size_t)b * PSTRIDE + p) * R_DP + r) * 64 + l) * C_DP + k;
        Dphase[off] = __float2half(exp2f(-d * L2E));
      }
    }
  }
}

// ---------------------------------------------------------------------------
// Kernel 3: wave-autonomous exp-domain soft-DTW DP, zero LDS, TRIPLE-buffered
// register staging. One wave (= block/CU) per batch: lane t owns rows
// 16t..16t+15; phase p handles chunk c = p - t. Handoff via shfl_up only.
// Loads: inline-asm global_load_dwordx4 into pinned register sets LA/LB/LC;
// s_waitcnt vmcnt(32) before consuming a set => the awaited loads were
// issued TWO full phases (~2-3k cyc) earlier — strictly covers L3/HBM
// latency (r11's depth-1 left ~1.6k cyc/phase exposed). sched_barrier(0)
// after each wait (rule #18). Math identical to the r5-verified recurrence.
// ---------------------------------------------------------------------------
__device__ inline void unpack8(uint4 v, float* e) {
  const __half2* h = reinterpret_cast<const __half2*>(&v);
  #pragma unroll
  for (int q = 0; q < 4; ++q) {
    float2 f = __half22float2(h[q]);
    e[2 * q] = f.x;
    e[2 * q + 1] = f.y;
  }
}

// issue 16 coalesced dwordx4 loads for one phase into register set L
#define ISSUE16(L, B0, B1, B2, B3)                                           \
  asm volatile("global_load_dwordx4 %0, %1, off"             : "=v"(L[0])  : "v"(B0)); \
  asm volatile("global_load_dwordx4 %0, %1, off offset:1024" : "=v"(L[1])  : "v"(B0)); \
  asm volatile("global_load_dwordx4 %0, %1, off offset:2048" : "=v"(L[2])  : "v"(B0)); \
  asm volatile("global_load_dwordx4 %0, %1, off offset:3072" : "=v"(L[3])  : "v"(B0)); \
  asm volatile("global_load_dwordx4 %0, %1, off"             : "=v"(L[4])  : "v"(B1)); \
  asm volatile("global_load_dwordx4 %0, %1, off offset:1024" : "=v"(L[5])  : "v"(B1)); \
  asm volatile("global_load_dwordx4 %0, %1, off offset:2048" : "=v"(L[6])  : "v"(B1)); \
  asm volatile("global_load_dwordx4 %0, %1, off offset:3072" : "=v"(L[7])  : "v"(B1)); \
  asm volatile("global_load_dwordx4 %0, %1, off"             : "=v"(L[8])  : "v"(B2)); \
  asm volatile("global_load_dwordx4 %0, %1, off offset:1024" : "=v"(L[9])  : "v"(B2)); \
  asm volatile("global_load_dwordx4 %0, %1, off offset:2048" : "=v"(L[10]) : "v"(B2)); \
  asm volatile("global_load_dwordx4 %0, %1, off offset:3072" : "=v"(L[11]) : "v"(B2)); \
  asm volatile("global_load_dwordx4 %0, %1, off"             : "=v"(L[12]) : "v"(B3)); \
  asm volatile("global_load_dwordx4 %0, %1, off offset:1024" : "=v"(L[13]) : "v"(B3)); \
  asm volatile("global_load_dwordx4 %0, %1, off offset:2048" : "=v"(L[14]) : "v"(B3)); \
  asm volatile("global_load_dwordx4 %0, %1, off offset:3072" : "=v"(L[15]) : "v"(B3));

#define ADV() { b0 += 16384; b1 += 16384; b2 += 16384; b3 += 16384; }

#define COMPUTE(P, L)                                                        \
  {                                                                          \
    int c = (P) - t;                                                         \
    float U[C_DP + 1];                                                       \
    _Pragma("unroll")                                                        \
    for (int k = 0; k <= C_DP; ++k) U[k] = __shfl_up(B[k], 1, 64);           \
    float Oin = __shfl_up(O, 1, 64);                                         \
    if (t == 0) {                                                            \
      _Pragma("unroll")                                                      \
      for (int k = 0; k <= C_DP; ++k) U[k] = 0.0f;                           \
      U[0] = (c == 0) ? 1.0f : 0.0f;                                         \
      Oin = O;                                                               \
    }                                                                        \
    if (c >= 0 && c < NCH) {                                                 \
      if (c == 0) O = Oin;                                                   \
      float sc = exp2f((O - Oin) * L2E);                                     \
      _Pragma("unroll")                                                      \
      for (int k = 0; k <= C_DP; ++k) U[k] *= sc;                            \
      _Pragma("unroll")                                                      \
      for (int r = 0; r < R_DP; ++r) {                                       \
        float e[C_DP];                                                       \
        unpack8(L[r], e);                                                    \
        float A[C_DP];                                                       \
        _Pragma("unroll")                                                    \
        for (int k = 0; k < C_DP; ++k) A[k] = e[k] * (U[k] + U[k + 1]);      \
        float oldc = carry[r];                                               \
        float left = oldc;                                                   \
        float V[C_DP];                                                       \
        _Pragma("unroll")                                                    \
        for (int k = 0; k < C_DP; ++k) {                                     \
          left = fmaf(e[k], left, A[k]);                                     \
          V[k] = left;                                                       \
        }                                                                    \
        U[0] = oldc;                                                         \
        _Pragma("unroll")                                                    \
        for (int k = 1; k <= C_DP; ++k) U[k] = V[k - 1];                     \
        carry[r] = V[C_DP - 1];                                              \
      }                                                                      \
      float rep = carry[R_DP - 1];                                           \
      if (rep > 0.0f) {                                                      \
        int ex = (int)((__float_as_uint(rep) >> 23) & 0xFF) - 127;           \
        if ((ex < -8 || ex > 8) && ex < 128) {                               \
          float s = __uint_as_float((unsigned)(127 - ex) << 23);             \
          _Pragma("unroll")                                                  \
          for (int r = 0; r < R_DP; ++r) carry[r] *= s;                      \
          _Pragma("unroll")                                                  \
          for (int k = 0; k <= C_DP; ++k) U[k] *= s;                         \
          O -= (float)ex * LN2;                                              \
        }                                                                    \
      }                                                                      \
      _Pragma("unroll")                                                      \
      for (int k = 0; k <= C_DP; ++k) B[k] = U[k];                           \
    }                                                                        \
  }

#define WAIT32()                                      \
  asm volatile("s_waitcnt vmcnt(32)" ::: "memory");   \
  __builtin_amdgcn_sched_barrier(0);

__global__ __launch_bounds__(64, 1) void dtw_kernel(
    const __half* __restrict__ Dphase, float* __restrict__ out) {
  int b = blockIdx.x;
  int t = threadIdx.x;                  // 0..63, lane = DP row-block owner

  // per-lane base for (phase 0, row 0): byte addr + t*16
  const char* g = (const char*)Dphase + (size_t)b * PSTRIDE * 16384 + t * 16;
  const char* b0 = g;                   // rows 0-3   (offsets 0..3072)
  const char* b1 = g + 4096;            // rows 4-7
  const char* b2 = g + 8192;            // rows 8-11
  const char* b3 = g + 12288;           // rows 12-15

  float carry[R_DP];
  #pragma unroll
  for (int r = 0; r < R_DP; ++r) carry[r] = 0.0f;
  float B[C_DP + 1] = {};
  float O = 0.0f;

  uint4 LA[R_DP], LB[R_DP], LC[R_DP];

  // prologue: issue phases 0 and 1
  ISSUE16(LA, b0, b1, b2, b3);
  ADV();
  ISSUE16(LB, b0, b1, b2, b3);

  for (int p = 0; p < 192; p += 3) {
    ADV();
    ISSUE16(LC, b0, b1, b2, b3);        // phase p+2
    WAIT32();
    COMPUTE(p, LA);

    ADV();
    ISSUE16(LA, b0, b1, b2, b3);        // phase p+3
    WAIT32();
    COMPUTE(p + 1, LB);

    ADV();
    ISSUE16(LB, b0, b1, b2, b3);        // phase p+4
    WAIT32();
    COMPUTE(p + 2, LC);
  }

  asm volatile("s_waitcnt vmcnt(0)" ::: "memory");

  if (t == 63) out[b] = O - logf(carry[R_DP - 1]);  // R[N][M]
}

// ---------------------------------------------------------------------------
extern "C" void kernel_launch(void* const* d_in, const int* in_sizes, int n_in,
                              void* d_out, int out_size, void* d_ws, size_t ws_size,
                              hipStream_t stream) {
  const float* x = (const float*)d_in[0];
  const float* y = (const float*)d_in[1];
  float* out = (float*)d_out;

  char* ws = (char*)d_ws;
  __half* Dphase = (__half*)ws;
  size_t dp_bytes = (size_t)BATCH * PSTRIDE * 16384;   // ~50.9 MB (incl. pad)
  unsigned short* xnb = (unsigned short*)(ws + dp_bytes);          // 4 MB
  unsigned short* ynb = xnb + (size_t)BATCH * NROW * DFEAT;        // 4 MB

  norm_kernel<<<(2 * BATCH * NROW) / 4, 256, 0, stream>>>(x, y, xnb, ynb);
  dist_kernel<<<dim3(MCOL / 128, NROW / 128, BATCH), 256, 0, stream>>>(
      xnb, ynb, Dphase);
  dtw_kernel<<<BATCH, 64, 0, stream>>>(Dphase, out);
}

// Round 13
// 268.602 us; speedup vs baseline: 1.0083x; 1.0083x over previous
//
#include <hip/hip_runtime.h>
#include <hip/hip_fp16.h>

#define BATCH 16
#define NROW 1024
#define MCOL 1024
#define DFEAT 128

// DP blocking: one wave per batch, 16 rows/thread, 8 cols/phase
#define R_DP 16
#define C_DP 8
#define NCH (MCOL / C_DP)   // 128 chunks along j
#define PSTRIDE 194         // phase slots per batch (incl. prefetch pad)

#define L2E 1.4426950408889634f
#define LN2 0.6931471805599453f

typedef __attribute__((ext_vector_type(8))) short short8;
typedef __attribute__((ext_vector_type(4))) float f32x4;

__device__ inline unsigned short f2bf(float f) {  // RNE f32 -> bf16 bits
  unsigned u = __float_as_uint(f);
  return (unsigned short)((u + 0x7fff + ((u >> 16) & 1)) >> 16);
}

// ---------------------------------------------------------------------------
// Kernel 1: normalize rows and emit bf16 copies. One wave per row.
// ---------------------------------------------------------------------------
__global__ __launch_bounds__(256) void norm_kernel(
    const float* __restrict__ x, const float* __restrict__ y,
    unsigned short* __restrict__ xnb, unsigned short* __restrict__ ynb) {
  int row = blockIdx.x * 4 + (threadIdx.x >> 6);
  int lane = threadIdx.x & 63;
  const float* src;
  unsigned short* dst;
  if (row < BATCH * NROW) {
    src = x + (size_t)row * DFEAT;
    dst = xnb + (size_t)row * DFEAT;
  } else {
    int r2 = row - BATCH * NROW;
    src = y + (size_t)r2 * DFEAT;
    dst = ynb + (size_t)r2 * DFEAT;
  }
  float2 v = *(const float2*)(src + lane * 2);
  float s = v.x * v.x + v.y * v.y;
  #pragma unroll
  for (int o = 32; o > 0; o >>= 1) s += __shfl_xor(s, o, 64);
  float inv = 1.0f / (sqrtf(s) + 1e-8f);
  unsigned short b0 = f2bf(v.x * inv), b1 = f2bf(v.y * inv);
  *(unsigned*)(dst + lane * 2) = (unsigned)b0 | ((unsigned)b1 << 16);
}

// ---------------------------------------------------------------------------
// Kernel 2: MFMA distance GEMM, 128x128 tile/block, phase-major fp16 output
// Dphase[b][p][r][lane][k], p = (j>>3) + (i>>4), r = i&15, k = j&7.
// ---------------------------------------------------------------------------
__global__ __launch_bounds__(256) void dist_kernel(
    const unsigned short* __restrict__ xnb, const unsigned short* __restrict__ ynb,
    __half* __restrict__ Dphase) {
  __shared__ __align__(16) unsigned char xsb[128 * 256];
  __shared__ __align__(16) unsigned char ysb[128 * 256];

  int b = blockIdx.z, ti0 = blockIdx.y, tj0 = blockIdx.x;
  int I0 = ti0 * 128, J0 = tj0 * 128;
  int tid = threadIdx.x;

  const uint4* xsrc = (const uint4*)(xnb + (size_t)(b * NROW + I0) * DFEAT);
  const uint4* ysrc = (const uint4*)(ynb + (size_t)(b * MCOL + J0) * DFEAT);
  #pragma unroll
  for (int it = 0; it < 8; ++it) {
    int idx = tid + it * 256;
    int row = idx >> 4, cb = (idx & 15) * 16;
    int swz = row * 256 + (cb ^ ((row & 7) << 4));
    *(uint4*)&xsb[swz] = xsrc[idx];
    *(uint4*)&ysb[swz] = ysrc[idx];
  }
  __syncthreads();

  int wid = tid >> 6, lane = tid & 63;
  int wi = wid >> 1, wj = wid & 1;
  int lr = lane & 15, lk = lane >> 4;

  f32x4 acc[4][4] = {};
  #pragma unroll
  for (int ks = 0; ks < 4; ++ks) {
    int cb = ks * 64 + lk * 16;
    short8 af[4], bf[4];
    #pragma unroll
    for (int ti = 0; ti < 4; ++ti) {
      int row = wi * 64 + ti * 16 + lr;
      af[ti] = *(short8*)&xsb[row * 256 + (cb ^ ((row & 7) << 4))];
    }
    #pragma unroll
    for (int tj = 0; tj < 4; ++tj) {
      int row = wj * 64 + tj * 16 + lr;
      bf[tj] = *(short8*)&ysb[row * 256 + (cb ^ ((row & 7) << 4))];
    }
    #pragma unroll
    for (int ti = 0; ti < 4; ++ti)
      #pragma unroll
      for (int tj = 0; tj < 4; ++tj)
        acc[ti][tj] = __builtin_amdgcn_mfma_f32_16x16x32_bf16(
            af[ti], bf[tj], acc[ti][tj], 0, 0, 0);
  }

  #pragma unroll
  for (int ti = 0; ti < 4; ++ti) {
    int gi0 = I0 + wi * 64 + ti * 16;
    int l = gi0 >> 4;
    #pragma unroll
    for (int tj = 0; tj < 4; ++tj) {
      int gj = J0 + wj * 64 + tj * 16 + lr;
      int c = gj >> 3, k = gj & 7;
      int p = c + l;
      #pragma unroll
      for (int v = 0; v < 4; ++v) {
        int r = lk * 4 + v;
        float d = 1.0f - acc[ti][tj][v];
        size_t off = ((((size_t)b * PSTRIDE + p) * R_DP + r) * 64 + l) * C_DP + k;
        Dphase[off] = __float2half(exp2f(-d * L2E));
      }
    }
  }
}

// ---------------------------------------------------------------------------
// Kernel 3: wave-autonomous exp-domain soft-DTW DP.
// r13 changes vs r12 (structure/math identical, overhead attacked):
//  - shfl_up -> DPP (row_shr:1 + row_bcast15 + cndmask): zero DS-pipe use
//  - fp16 cells consumed via v_fma_mix_f32 (op_sel reads f16 halves): no cvt
//  - loads via SGPR-base + constant voffset (addr advance on SALU)
//  - renorm window widened to [-20, +12] (fires ~every 2 phases)
//  - unguarded fast body for phases 64..127 (all lanes active)
// ---------------------------------------------------------------------------
__device__ __forceinline__ float shup(float x, bool edge) {
  int xi = __float_as_int(x);
  int sh = __builtin_amdgcn_update_dpp(xi, xi, 0x111, 0xF, 0xF, false); // row_shr:1
  int bc = __builtin_amdgcn_update_dpp(xi, xi, 0x142, 0xF, 0xF, false); // row_bcast15
  return __int_as_float(edge ? bc : sh);
}

// A = f16(lo/hi of h) * s      (fzero VGPR)
#define MIXMUL_LO(A, h, s) \
  asm("v_fma_mix_f32 %0, %1, %2, %3 op_sel_hi:[1,0,0]" : "=v"(A) : "v"(h), "v"(s), "v"(fzero))
#define MIXMUL_HI(A, h, s) \
  asm("v_fma_mix_f32 %0, %1, %2, %3 op_sel:[1,0,0] op_sel_hi:[1,0,0]" : "=v"(A) : "v"(h), "v"(s), "v"(fzero))
// lf = f16(lo/hi of h) * lf + a
#define MIXFMA_LO(lf, h, a) \
  asm("v_fma_mix_f32 %0, %1, %2, %3 op_sel_hi:[1,0,0]" : "=v"(lf) : "v"(h), "v"(lf), "v"(a))
#define MIXFMA_HI(lf, h, a) \
  asm("v_fma_mix_f32 %0, %1, %2, %3 op_sel:[1,0,0] op_sel_hi:[1,0,0]" : "=v"(lf) : "v"(h), "v"(lf), "v"(a))

template<bool GUARDED>
__device__ __forceinline__ void dtw_phase(int c, int t, bool edge,
    const uint4* L, float* carry, float (&B)[9], float& O, float fzero) {
  float U[9];
  #pragma unroll
  for (int k = 0; k < 9; ++k) U[k] = shup(B[k], edge);
  float Oin = shup(O, edge);
  if (t == 0) {
    #pragma unroll
    for (int k = 0; k < 9; ++k) U[k] = 0.0f;
    if (GUARDED && c == 0) U[0] = 1.0f;   // E[0][0] = exp(-0)
    Oin = O;
  }
  bool act = GUARDED ? (c >= 0 && c < NCH) : true;
  if (act) {
    if (GUARDED && c == 0) O = Oin;       // adopt neighbor's frame
    float sc = exp2f((O - Oin) * L2E);
    #pragma unroll
    for (int k = 0; k < 9; ++k) U[k] *= sc;

    #pragma unroll
    for (int r = 0; r < R_DP; ++r) {
      uint4 d = L[r];
      unsigned dw[4] = {d.x, d.y, d.z, d.w};
      float S[8], A[8];
      #pragma unroll
      for (int k = 0; k < 8; ++k) S[k] = U[k] + U[k + 1];
      #pragma unroll
      for (int q = 0; q < 4; ++q) {
        MIXMUL_LO(A[2 * q],     dw[q], S[2 * q]);
        MIXMUL_HI(A[2 * q + 1], dw[q], S[2 * q + 1]);
      }
      float oldc = carry[r], lf = oldc;
      float V[8];
      #pragma unroll
      for (int q = 0; q < 4; ++q) {
        MIXFMA_LO(lf, dw[q], A[2 * q]);     V[2 * q] = lf;
        MIXFMA_HI(lf, dw[q], A[2 * q + 1]); V[2 * q + 1] = lf;
      }
      U[0] = oldc;
      #pragma unroll
      for (int k = 1; k <= 8; ++k) U[k] = V[k - 1];
      carry[r] = lf;
    }

    // renorm: E *= 2^-ex  =>  O -= ex*ln2 ; window [-20,+12]
    float rep = carry[R_DP - 1];
    int ex = (int)((__float_as_uint(rep) >> 23) & 0xFF) - 127;
    if ((ex < -20 || ex > 12) && ex < 128) {
      float s = __uint_as_float((unsigned)(127 - ex) << 23);  // 2^-ex
      #pragma unroll
      for (int r = 0; r < R_DP; ++r) carry[r] *= s;
      #pragma unroll
      for (int k = 0; k < 9; ++k) U[k] *= s;
      O -= (float)ex * LN2;
    }
    #pragma unroll
    for (int k = 0; k < 9; ++k) B[k] = U[k];
  }
}

#define GL(Lr, SB, OFF) \
  asm volatile("global_load_dwordx4 %0, %1, %2 offset:" OFF : "=v"(Lr) : "v"(voff), "s"(SB));

#define ISSUE16(L)                                               \
  GL(L[0],  s0, "0")    GL(L[1],  s0, "1024")                    \
  GL(L[2],  s0, "2048") GL(L[3],  s0, "3072")                    \
  GL(L[4],  s1, "0")    GL(L[5],  s1, "1024")                    \
  GL(L[6],  s1, "2048") GL(L[7],  s1, "3072")                    \
  GL(L[8],  s2, "0")    GL(L[9],  s2, "1024")                    \
  GL(L[10], s2, "2048") GL(L[11], s2, "3072")                    \
  GL(L[12], s3, "0")    GL(L[13], s3, "1024")                    \
  GL(L[14], s3, "2048") GL(L[15], s3, "3072")

#define ADV() { s0 += 16384; s1 += 16384; s2 += 16384; s3 += 16384; }

#define WAITC()                                       \
  asm volatile("s_waitcnt vmcnt(16)" ::: "memory");   \
  __builtin_amdgcn_sched_barrier(0);

#define STEP2(PP, G)                                                        \
  ADV(); ISSUE16(LB);                                                       \
  WAITC(); dtw_phase<G>((PP) - t, t, edge, LA, carry, B, O, fzero);         \
  ADV(); ISSUE16(LA);                                                       \
  WAITC(); dtw_phase<G>((PP) + 1 - t, t, edge, LB, carry, B, O, fzero);

__global__ __launch_bounds__(64, 1) void dtw_kernel(
    const __half* __restrict__ Dphase, float* __restrict__ out) {
  int b = blockIdx.x;
  int t = threadIdx.x;
  const bool edge = (t != 0) && ((t & 15) == 0);
  float fzero = 0.0f;
  int voff = t * 16;                     // per-lane, loop-invariant

  // uniform SGPR bases for row groups 0-3 / 4-7 / 8-11 / 12-15
  const char* g = (const char*)Dphase + (size_t)b * PSTRIDE * 16384;
  const char* s0 = g;
  const char* s1 = g + 4096;
  const char* s2 = g + 8192;
  const char* s3 = g + 12288;

  float carry[R_DP];
  #pragma unroll
  for (int r = 0; r < R_DP; ++r) carry[r] = 0.0f;
  float B[9] = {};
  float O = 0.0f;

  uint4 LA[R_DP], LB[R_DP];
  ISSUE16(LA);                           // phase 0

  for (int p = 0; p < 64; p += 2)   { STEP2(p, true); }
  for (int p = 64; p < 128; p += 2) { STEP2(p, false); }
  for (int p = 128; p < 192; p += 2){ STEP2(p, true); }

  asm volatile("s_waitcnt vmcnt(0)" ::: "memory");

  if (t == 63) out[b] = O - logf(carry[R_DP - 1]);  // R[N][M]
}

// ---------------------------------------------------------------------------
extern "C" void kernel_launch(void* const* d_in, const int* in_sizes, int n_in,
                              void* d_out, int out_size, void* d_ws, size_t ws_size,
                              hipStream_t stream) {
  const float* x = (const float*)d_in[0];
  const float* y = (const float*)d_in[1];
  float* out = (float*)d_out;

  char* ws = (char*)d_ws;
  __half* Dphase = (__half*)ws;
  size_t dp_bytes = (size_t)BATCH * PSTRIDE * 16384;   // ~50.9 MB
  unsigned short* xnb = (unsigned short*)(ws + dp_bytes);          // 4 MB
  unsigned short* ynb = xnb + (size_t)BATCH * NROW * DFEAT;        // 4 MB

  norm_kernel<<<(2 * BATCH * NROW) / 4, 256, 0, stream>>>(x, y, xnb, ynb);
  dist_kernel<<<dim3(MCOL / 128, NROW / 128, BATCH), 256, 0, stream>>>(
      xnb, ynb, Dphase);
  dtw_kernel<<<BATCH, 64, 0, stream>>>(Dphase, out);
}